// Round 3
// baseline (5516.897 us; speedup 1.0000x reference)
//
#include <hip/hip_runtime.h>

// LinearRNNwithSoftExp on MI355X (gfx950)  T=1024, B=512, D=128, H=256.
// Round 5: shorten the per-step critical path (lockstep waves can't hide it).
//  - accumulation chains split: recurrent depth 8 -> 4+4 (ra/rb), xproj 4 -> 2+2
//  - epilogue algebra: u = fma(pp, inv, al + xs - inv)  [= (pp-1)*inv + al + xs]
//  - h-state hi/lo packing via v_cvt_pk_bf16_f32 (2 instr vs ~22 scalar VALU)
//  - data staging distributed across all 16 waves (lane<16, 1 elem each)
//  - xproj issued first after barrier to fill MFMA pipe while h ds_reads land
// Kept from round 4: 16 waves, wave w owns 16 cols; hi/lo bf16 h fold in
// A-rows 0..3; 2-step-ahead data prefetch; 1 barrier/step.

#define BB 512
#define DD 128
#define HH 256

typedef __attribute__((ext_vector_type(8))) short bf16x8;
typedef __attribute__((ext_vector_type(4))) float f32x4;

static __device__ __forceinline__ short f2bf(float f) {
    unsigned u = __float_as_uint(f);
    u += 0x7FFFu + ((u >> 16) & 1u);   // round-to-nearest-even
    return (short)(u >> 16);
}
static __device__ __forceinline__ bf16x8 pack8(const float4 a, const float4 b) {
    bf16x8 v;
    v[0] = f2bf(a.x); v[1] = f2bf(a.y); v[2] = f2bf(a.z); v[3] = f2bf(a.w);
    v[4] = f2bf(b.x); v[5] = f2bf(b.y); v[6] = f2bf(b.z); v[7] = f2bf(b.w);
    return v;
}

__global__ __launch_bounds__(1024, 4)
void rnn_fused(const float* __restrict__ data, const float* __restrict__ ih_w,
               const float* __restrict__ ih_b, const float* __restrict__ hh_w,
               const float* __restrict__ hh_b, const int* __restrict__ lengths,
               float* __restrict__ out)
{
    const int g    = blockIdx.x;
    const int tid  = threadIdx.x;
    const int w    = tid >> 6;     // wave 0..15
    const int lane = tid & 63;
    const int col  = lane & 15;    // MFMA n-col / A-row index
    const int quad = lane >> 4;    // k-quad

    // h state, bf16 hi+lo folded into A-rows:
    // [ping][kf = k/8][row: 0=h0hi 1=h1hi 2=h0lo 3=h1lo][slot = k%8]
    __shared__ short hbuf[2][32][4][8];
    // data staging, bf16: [ping][row(2)][k(128)]
    __shared__ short dbuf[2][2][DD];

    // ---- persistent weight fragments in registers ----
    // whh[s][i]: s=0 alpha row 16w+col, s=1 hbar row 256+16w+col
    bf16x8 whh[2][8];
    #pragma unroll
    for (int s = 0; s < 2; ++s) {
        const int wrow = s*HH + 16*w + col;
        const float* src = hh_w + wrow * HH;
        #pragma unroll
        for (int i = 0; i < 8; ++i) {
            const float4 a = *(const float4*)(src + i*32 + quad*8);
            const float4 b = *(const float4*)(src + i*32 + quad*8 + 4);
            whh[s][i] = pack8(a, b);
        }
    }
    bf16x8 wih[4];
    {
        const int wrow = 16*w + col;
        const float* src = ih_w + wrow * DD;
        #pragma unroll
        for (int i = 0; i < 4; ++i) {
            const float4 a = *(const float4*)(src + i*32 + quad*8);
            const float4 b = *(const float4*)(src + i*32 + quad*8 + 4);
            wih[i] = pack8(a, b);
        }
    }

    const float bA = hh_b[      16*w + col];
    const float bH = hh_b[HH  + 16*w + col];
    const float bX = ih_b[      16*w + col];

    const int L0 = lengths[2*g];
    const int L1 = lengths[2*g + 1];
    const int Lmax = (L0 > L1) ? L0 : L1;

    // staging: lane<16 (quad==0) of wave w owns data element w*16+col
    const bool smine = (quad == 0);
    const int  se    = (w << 4) | col;

    // ---- prologue: zero h ping 0, stage data[0], prefetch data[1] ----
    for (int idx = tid; idx < 32*4*8; idx += 1024)
        ((short*)hbuf[0])[idx] = 0;
    if (smine)
        ((short*)dbuf[0])[se] = f2bf(data[(size_t)(2*g) * DD + se]);
    float vstage = 0.f;
    if (smine && 1 < Lmax)
        vstage = data[((size_t)1 * BB + 2*g) * DD + se];
    __syncthreads();

    float  nh[2] = {0.f, 0.f};
    bf16x8 hf[4]  = {};   // h A-frags half 0 (col<4 lanes)
    bf16x8 hf2[4] = {};   // h A-frags half 1
    bf16x8 df[4]  = {};   // data A-frags (col<2 lanes)

    const bool acth = (col < 4);   // A-rows 0..3 real for recurrent matmul
    const bool actd = (col < 2);   // A-rows 0..1 real for x-projection

    for (int t = 0; t < Lmax; ++t) {
        const int p = t & 1;

        // ---- publish data[t+1] (loaded a full step ago), issue data[t+2]
        if (smine && t + 1 < Lmax)
            ((short*)dbuf[1 - p])[se] = f2bf(vstage);
        float vnew = 0.f;
        if (smine && t + 2 < Lmax)
            vnew = data[((size_t)(t+2) * BB + 2*g) * DD + se];

        // ---- x-projection first (independent of h): 2 chains of depth 2
        if (actd) {
            #pragma unroll
            for (int i = 0; i < 4; ++i)
                df[i] = *(const bf16x8*)&dbuf[p][col][i*32 + quad*8];
        }
        f32x4 xa  = {0.f,0.f,0.f,0.f};
        f32x4 xa2 = {0.f,0.f,0.f,0.f};
        xa  = __builtin_amdgcn_mfma_f32_16x16x32_bf16(df[0], wih[0], xa , 0,0,0);
        xa2 = __builtin_amdgcn_mfma_f32_16x16x32_bf16(df[1], wih[1], xa2, 0,0,0);
        xa  = __builtin_amdgcn_mfma_f32_16x16x32_bf16(df[2], wih[2], xa , 0,0,0);
        xa2 = __builtin_amdgcn_mfma_f32_16x16x32_bf16(df[3], wih[3], xa2, 0,0,0);

        // ---- recurrent matmul: half 0 -> ra, half 1 -> rb (depth 4 each)
        f32x4 ra[2] = {{0.f,0.f,0.f,0.f},{0.f,0.f,0.f,0.f}};
        f32x4 rb[2] = {{0.f,0.f,0.f,0.f},{0.f,0.f,0.f,0.f}};
        if (acth) {
            #pragma unroll
            for (int i = 0; i < 4; ++i)
                hf[i]  = *(const bf16x8*)&hbuf[p][i*4 + quad][col][0];
            #pragma unroll
            for (int i = 0; i < 4; ++i)
                hf2[i] = *(const bf16x8*)&hbuf[p][(4 + i)*4 + quad][col][0];
        }
        #pragma unroll
        for (int i = 0; i < 4; ++i)
            #pragma unroll
            for (int s = 0; s < 2; ++s)
                ra[s] = __builtin_amdgcn_mfma_f32_16x16x32_bf16(
                    hf[i], whh[s][i], ra[s], 0, 0, 0);
        #pragma unroll
        for (int i = 0; i < 4; ++i)
            #pragma unroll
            for (int s = 0; s < 2; ++s)
                rb[s] = __builtin_amdgcn_mfma_f32_16x16x32_bf16(
                    hf2[i], whh[s][4 + i], rb[s], 0, 0, 0);

        // ---- epilogue: combine, sigmoid, soft-exp, tanh, mask ----
        // C/D layout: col = lane&15, row = quad*4 + reg; rows 0..3 in quad 0.
        float vres[2];
        #pragma unroll
        for (int r = 0; r < 2; ++r) {
            const float a   = (ra[0][r] + ra[0][2+r]) + (rb[0][r] + rb[0][2+r]) + bA;
            const float hv  = (ra[1][r] + ra[1][2+r]) + (rb[1][r] + rb[1][2+r]) + bH;
            const float e   = __builtin_amdgcn_exp2f(a * -1.4426950408889634f);
            const float inv = 1.0f + e;                    // exactly 1/alpha
            const float al  = __builtin_amdgcn_rcpf(inv);  // alpha
            const float xs  = (xa[r] + xa2[r]) + bX;       // off critical chain
            const float c1  = al + xs - inv;               // while pp in flight
            const float pp  = __builtin_amdgcn_exp2f(al * hv);
            const float u   = __builtin_fmaf(pp, inv, c1); // (pp-1)*inv+al+xs
            const float t2  = __builtin_amdgcn_exp2f(u * 2.8853900817779268f);
            const float th  = 1.0f - 2.0f * __builtin_amdgcn_rcpf(1.0f + t2);
            const int   Lr  = r ? L1 : L0;
            vres[r] = (t < Lr) ? th : nh[r];
            nh[r]   = vres[r];
        }

        // ---- pack hi/lo with v_cvt_pk_bf16_f32 (RNE), 4 b16 stores ----
        unsigned pkhi, pklo;
        asm("v_cvt_pk_bf16_f32 %0, %1, %2"
            : "=v"(pkhi) : "v"(vres[0]), "v"(vres[1]));
        const float b0 = __uint_as_float(pkhi << 16);
        const float b1 = __uint_as_float(pkhi & 0xFFFF0000u);
        asm("v_cvt_pk_bf16_f32 %0, %1, %2"
            : "=v"(pklo) : "v"(vres[0] - b0), "v"(vres[1] - b1));
        if (quad == 0) {
            const int c = 16*w + col;           // h element index 0..255
            short* hb = &hbuf[1 - p][c >> 3][0][c & 7];
            hb[0]  = (short)(pkhi & 0xFFFFu);
            hb[8]  = (short)(pkhi >> 16);
            hb[16] = (short)(pklo & 0xFFFFu);
            hb[24] = (short)(pklo >> 16);
        }

        vstage = vnew;
        __syncthreads();
    }

    // ---- final hidden state -> out [1, B, H] fp32 ----
    if (quad == 0) {
        #pragma unroll
        for (int r = 0; r < 2; ++r)
            out[(size_t)(2*g + r) * HH + 16*w + col] = nh[r];
    }
}

extern "C" void kernel_launch(void* const* d_in, const int* in_sizes, int n_in,
                              void* d_out, int out_size, void* d_ws, size_t ws_size,
                              hipStream_t stream) {
    const float* data    = (const float*)d_in[0];
    const float* ih_w    = (const float*)d_in[1];
    const float* ih_b    = (const float*)d_in[2];
    const float* hh_w    = (const float*)d_in[3];
    const float* hh_b    = (const float*)d_in[4];
    const int*   lengths = (const int*)d_in[5];
    float* out = (float*)d_out;

    (void)in_sizes; (void)n_in; (void)out_size; (void)d_ws; (void)ws_size;

    rnn_fused<<<dim3(BB / 2), dim3(1024), 0, stream>>>(
        data, ih_w, ih_b, hh_w, hh_b, lengths, out);
}

// Round 4
// 1341.243 us; speedup vs baseline: 4.1133x; 4.1133x over previous
//
#include <hip/hip_runtime.h>

// LinearRNNwithSoftExp on MI355X (gfx950)  T=1024, B=512, D=128, H=256.
// Round 6: recover from round-5 spill catastrophe (FETCH 5.5GB = weight frags
// spilled to scratch, re-read every step; launch_bounds(1024,4) caps V+A at
// 128/wave and the 3 separate frag arrays blew it). Revert to round-4 register
// structure: ONE shared frag[4] for h and data A-frags, racc[2] depth-8,
// single xacc. Keep only cheap round-5 wins (all correctness-verified there):
//  - v_cvt_pk_bf16_f32 hi/lo h-state packing (~16 VALU/step saved)
//  - epilogue algebra u = fma(pp, inv, al + xs - inv); xs off critical chain
//  - data staging distributed: lane<16 of every wave owns 1 element (no
//    wave-0..3 straggler skew at the barrier)
// Kept from round 4: 16 waves, wave w owns 16 cols; hi/lo bf16 h fold in
// A-rows 0..3; 2-step-ahead data prefetch; 1 barrier/step.

#define BB 512
#define DD 128
#define HH 256

typedef __attribute__((ext_vector_type(8))) short bf16x8;
typedef __attribute__((ext_vector_type(4))) float f32x4;

static __device__ __forceinline__ short f2bf(float f) {
    unsigned u = __float_as_uint(f);
    u += 0x7FFFu + ((u >> 16) & 1u);   // round-to-nearest-even
    return (short)(u >> 16);
}
static __device__ __forceinline__ bf16x8 pack8(const float4 a, const float4 b) {
    bf16x8 v;
    v[0] = f2bf(a.x); v[1] = f2bf(a.y); v[2] = f2bf(a.z); v[3] = f2bf(a.w);
    v[4] = f2bf(b.x); v[5] = f2bf(b.y); v[6] = f2bf(b.z); v[7] = f2bf(b.w);
    return v;
}

__global__ __launch_bounds__(1024, 4)
void rnn_fused(const float* __restrict__ data, const float* __restrict__ ih_w,
               const float* __restrict__ ih_b, const float* __restrict__ hh_w,
               const float* __restrict__ hh_b, const int* __restrict__ lengths,
               float* __restrict__ out)
{
    const int g    = blockIdx.x;
    const int tid  = threadIdx.x;
    const int w    = tid >> 6;     // wave 0..15
    const int lane = tid & 63;
    const int col  = lane & 15;    // MFMA n-col / A-row index
    const int quad = lane >> 4;    // k-quad

    // h state, bf16 hi+lo folded into A-rows:
    // [ping][kf = k/8][row: 0=h0hi 1=h1hi 2=h0lo 3=h1lo][slot = k%8]
    __shared__ short hbuf[2][32][4][8];
    // data staging, bf16: [ping][row(2)][k(128)]
    __shared__ short dbuf[2][2][DD];

    // ---- persistent weight fragments in registers ----
    // whh[s][i]: s=0 alpha row 16w+col, s=1 hbar row 256+16w+col
    bf16x8 whh[2][8];
    #pragma unroll
    for (int s = 0; s < 2; ++s) {
        const int wrow = s*HH + 16*w + col;
        const float* src = hh_w + wrow * HH;
        #pragma unroll
        for (int i = 0; i < 8; ++i) {
            const float4 a = *(const float4*)(src + i*32 + quad*8);
            const float4 b = *(const float4*)(src + i*32 + quad*8 + 4);
            whh[s][i] = pack8(a, b);
        }
    }
    bf16x8 wih[4];
    {
        const int wrow = 16*w + col;
        const float* src = ih_w + wrow * DD;
        #pragma unroll
        for (int i = 0; i < 4; ++i) {
            const float4 a = *(const float4*)(src + i*32 + quad*8);
            const float4 b = *(const float4*)(src + i*32 + quad*8 + 4);
            wih[i] = pack8(a, b);
        }
    }

    const float bA = hh_b[      16*w + col];
    const float bH = hh_b[HH  + 16*w + col];
    const float bX = ih_b[      16*w + col];

    const int L0 = lengths[2*g];
    const int L1 = lengths[2*g + 1];
    const int Lmax = (L0 > L1) ? L0 : L1;

    // staging: lane<16 (quad==0) of wave w owns data element w*16+col
    const bool smine = (quad == 0);
    const int  se    = (w << 4) | col;

    // ---- prologue: zero h ping 0, stage data[0], prefetch data[1] ----
    for (int idx = tid; idx < 32*4*8; idx += 1024)
        ((short*)hbuf[0])[idx] = 0;
    if (smine)
        ((short*)dbuf[0])[se] = f2bf(data[(size_t)(2*g) * DD + se]);
    float vstage = 0.f;
    if (smine && 1 < Lmax)
        vstage = data[((size_t)1 * BB + 2*g) * DD + se];
    __syncthreads();

    float  nh[2] = {0.f, 0.f};
    bf16x8 frag[4] = {};   // shared A-frags: h (col<4) then data (col<2)

    const bool acth = (col < 4);   // A-rows 0..3 real for recurrent matmul
    const bool actd = (col < 2);   // A-rows 0..1 real for x-projection

    for (int t = 0; t < Lmax; ++t) {
        const int p = t & 1;

        // ---- publish data[t+1] (loaded a full step ago), issue data[t+2]
        if (smine && t + 1 < Lmax)
            ((short*)dbuf[1 - p])[se] = f2bf(vstage);
        float vnew = 0.f;
        if (smine && t + 2 < Lmax)
            vnew = data[((size_t)(t+2) * BB + 2*g) * DD + se];

        // ---- recurrent matmul: hi in C-rows 0..1, lo in 2..3, zero C-init
        f32x4 racc[2] = {{0.f,0.f,0.f,0.f},{0.f,0.f,0.f,0.f}};
        #pragma unroll
        for (int half = 0; half < 2; ++half) {      // k-frags 0-3, 4-7
            if (acth) {
                #pragma unroll
                for (int i = 0; i < 4; ++i)
                    frag[i] = *(const bf16x8*)
                        &hbuf[p][(half*4 + i)*4 + quad][col][0];
            }
            #pragma unroll
            for (int i = 0; i < 4; ++i)
                #pragma unroll
                for (int s = 0; s < 2; ++s)
                    racc[s] = __builtin_amdgcn_mfma_f32_16x16x32_bf16(
                        frag[i], whh[s][half*4 + i], racc[s], 0, 0, 0);
        }

        // ---- x-projection: data[t] @ ih_w^T (bias folded below) ----
        if (actd) {
            #pragma unroll
            for (int i = 0; i < 4; ++i)
                frag[i] = *(const bf16x8*)&dbuf[p][col][i*32 + quad*8];
        }
        f32x4 xacc = {0.f, 0.f, 0.f, 0.f};
        #pragma unroll
        for (int i = 0; i < 4; ++i)
            xacc = __builtin_amdgcn_mfma_f32_16x16x32_bf16(
                frag[i], wih[i], xacc, 0, 0, 0);

        // ---- epilogue: combine hi+lo+bias, sigmoid, soft-exp, tanh, mask
        // C/D layout: col = lane&15, row = quad*4 + reg; rows 0..3 in quad 0.
        float vres[2];
        #pragma unroll
        for (int r = 0; r < 2; ++r) {
            const float a   = racc[0][r] + racc[0][2 + r] + bA;
            const float hv  = racc[1][r] + racc[1][2 + r] + bH;
            const float e   = __builtin_amdgcn_exp2f(a * -1.4426950408889634f);
            const float inv = 1.0f + e;                    // exactly 1/alpha
            const float al  = __builtin_amdgcn_rcpf(inv);  // alpha
            const float xs  = xacc[r] + bX;                // off critical chain
            const float c1  = al + xs - inv;               // while pp in flight
            const float pp  = __builtin_amdgcn_exp2f(al * hv);
            const float u   = __builtin_fmaf(pp, inv, c1); // (pp-1)*inv+al+xs
            const float t2  = __builtin_amdgcn_exp2f(u * 2.8853900817779268f);
            const float th  = 1.0f - 2.0f * __builtin_amdgcn_rcpf(1.0f + t2);
            const int   Lr  = r ? L1 : L0;
            vres[r] = (t < Lr) ? th : nh[r];
            nh[r]   = vres[r];
        }

        // ---- pack hi/lo with v_cvt_pk_bf16_f32 (RNE), 4 b16 stores ----
        unsigned pkhi, pklo;
        asm("v_cvt_pk_bf16_f32 %0, %1, %2"
            : "=v"(pkhi) : "v"(vres[0]), "v"(vres[1]));
        const float b0 = __uint_as_float(pkhi << 16);
        const float b1 = __uint_as_float(pkhi & 0xFFFF0000u);
        asm("v_cvt_pk_bf16_f32 %0, %1, %2"
            : "=v"(pklo) : "v"(vres[0] - b0), "v"(vres[1] - b1));
        if (quad == 0) {
            const int c = 16*w + col;           // h element index 0..255
            short* hb = &hbuf[1 - p][c >> 3][0][c & 7];
            hb[0]  = (short)(pkhi & 0xFFFFu);
            hb[8]  = (short)(pkhi >> 16);
            hb[16] = (short)(pklo & 0xFFFFu);
            hb[24] = (short)(pklo >> 16);
        }

        vstage = vnew;
        __syncthreads();
    }

    // ---- final hidden state -> out [1, B, H] fp32 ----
    if (quad == 0) {
        #pragma unroll
        for (int r = 0; r < 2; ++r)
            out[(size_t)(2*g + r) * HH + 16*w + col] = nh[r];
    }
}

extern "C" void kernel_launch(void* const* d_in, const int* in_sizes, int n_in,
                              void* d_out, int out_size, void* d_ws, size_t ws_size,
                              hipStream_t stream) {
    const float* data    = (const float*)d_in[0];
    const float* ih_w    = (const float*)d_in[1];
    const float* ih_b    = (const float*)d_in[2];
    const float* hh_w    = (const float*)d_in[3];
    const float* hh_b    = (const float*)d_in[4];
    const int*   lengths = (const int*)d_in[5];
    float* out = (float*)d_out;

    (void)in_sizes; (void)n_in; (void)out_size; (void)d_ws; (void)ws_size;

    rnn_fused<<<dim3(BB / 2), dim3(1024), 0, stream>>>(
        data, ih_w, ih_b, hh_w, hh_b, lengths, out);
}

// Round 5
// 1273.615 us; speedup vs baseline: 4.3317x; 1.0531x over previous
//
#include <hip/hip_runtime.h>

// LinearRNNwithSoftExp on MI355X (gfx950)  T=1024, B=512, D=128, H=256.
// Round 7: halve the epilogue issue width + cheaper barrier + setprio.
//  - 32-lane epilogue: combine hi+lo rows in-lane, ds_swizzle (XOR 16) moves
//    row-1 (a,hv,x) from quad0 to quad1 lanes; ONE epilogue pass on lanes
//    0..31 (row = quad) instead of an r-loop on 16 lanes. Trans ops 10->5.
//  - raw s_barrier + asm lgkmcnt(0): no vmcnt(0) drain, data prefetch stays
//    in flight across the barrier.
//  - s_setprio(1) around the MFMA cluster (waves drift at epilogue/barrier).
// Register budget is EXACTLY at the 128 combined VGPR+AGPR cap (whh/wih live
// in AGPRs; round 5 proved +32 live regs = spill catastrophe). This round is
// register-neutral: r-loop removal kills vres[2]/nh[2]; swizzle temps are
// short-lived. Keep the ONE shared frag[4] for h and data A-frags.
// Kept: 16 waves, wave owns 16 cols; hi/lo bf16 h fold in A-rows 0..3;
// 2-step-ahead data prefetch; 1 barrier/step; numerics bit-identical.

#define BB 512
#define DD 128
#define HH 256

typedef __attribute__((ext_vector_type(8))) short bf16x8;
typedef __attribute__((ext_vector_type(4))) float f32x4;

static __device__ __forceinline__ short f2bf(float f) {
    unsigned u = __float_as_uint(f);
    u += 0x7FFFu + ((u >> 16) & 1u);   // round-to-nearest-even
    return (short)(u >> 16);
}
static __device__ __forceinline__ bf16x8 pack8(const float4 a, const float4 b) {
    bf16x8 v;
    v[0] = f2bf(a.x); v[1] = f2bf(a.y); v[2] = f2bf(a.z); v[3] = f2bf(a.w);
    v[4] = f2bf(b.x); v[5] = f2bf(b.y); v[6] = f2bf(b.z); v[7] = f2bf(b.w);
    return v;
}
static __device__ __forceinline__ float swz16(float x) {
    // lane l <- lane l^16 (BitMode: and=0x1F, or=0, xor=16)
    return __uint_as_float((unsigned)__builtin_amdgcn_ds_swizzle(
        (int)__float_as_uint(x), 0x401F));
}

__global__ __launch_bounds__(1024, 4)
void rnn_fused(const float* __restrict__ data, const float* __restrict__ ih_w,
               const float* __restrict__ ih_b, const float* __restrict__ hh_w,
               const float* __restrict__ hh_b, const int* __restrict__ lengths,
               float* __restrict__ out)
{
    const int g    = blockIdx.x;
    const int tid  = threadIdx.x;
    const int w    = tid >> 6;     // wave 0..15
    const int lane = tid & 63;
    const int col  = lane & 15;    // MFMA n-col / A-row index
    const int quad = lane >> 4;    // k-quad

    // h state, bf16 hi+lo folded into A-rows:
    // [ping][kf = k/8][row: 0=h0hi 1=h1hi 2=h0lo 3=h1lo][slot = k%8]
    __shared__ short hbuf[2][32][4][8];
    // data staging, bf16: [ping][row(2)][k(128)]
    __shared__ short dbuf[2][2][DD];

    // ---- persistent weight fragments in registers ----
    // whh[s][i]: s=0 alpha row 16w+col, s=1 hbar row 256+16w+col
    bf16x8 whh[2][8];
    #pragma unroll
    for (int s = 0; s < 2; ++s) {
        const int wrow = s*HH + 16*w + col;
        const float* src = hh_w + wrow * HH;
        #pragma unroll
        for (int i = 0; i < 8; ++i) {
            const float4 a = *(const float4*)(src + i*32 + quad*8);
            const float4 b = *(const float4*)(src + i*32 + quad*8 + 4);
            whh[s][i] = pack8(a, b);
        }
    }
    bf16x8 wih[4];
    {
        const int wrow = 16*w + col;
        const float* src = ih_w + wrow * DD;
        #pragma unroll
        for (int i = 0; i < 4; ++i) {
            const float4 a = *(const float4*)(src + i*32 + quad*8);
            const float4 b = *(const float4*)(src + i*32 + quad*8 + 4);
            wih[i] = pack8(a, b);
        }
    }

    const float bA = hh_b[      16*w + col];
    const float bH = hh_b[HH  + 16*w + col];
    const float bX = ih_b[      16*w + col];

    const int L0 = lengths[2*g];
    const int L1 = lengths[2*g + 1];
    const int Lmax = (L0 > L1) ? L0 : L1;

    // staging: lane<16 (quad==0) of wave w owns data element w*16+col
    const bool smine = (quad == 0);
    const int  se    = (w << 4) | col;

    // ---- prologue: zero h ping 0, stage data[0], prefetch data[1] ----
    for (int idx = tid; idx < 32*4*8; idx += 1024)
        ((short*)hbuf[0])[idx] = 0;
    if (smine)
        ((short*)dbuf[0])[se] = f2bf(data[(size_t)(2*g) * DD + se]);
    float vstage = 0.f;
    if (smine && 1 < Lmax)
        vstage = data[((size_t)1 * BB + 2*g) * DD + se];
    __syncthreads();

    float  nhv = 0.f;      // lanes<32: h[row=quad][16w+col]
    bf16x8 frag[4] = {};   // shared A-frags: h (col<4) then data (col<2)

    const bool acth = (col < 4);   // A-rows 0..3 real for recurrent matmul
    const bool actd = (col < 2);   // A-rows 0..1 real for x-projection
    const int  rq   = quad & 1;    // row owned by this lane (lanes<32)
    const int  Lr   = rq ? L1 : L0;

    for (int t = 0; t < Lmax; ++t) {
        const int p = t & 1;

        // ---- publish data[t+1] (loaded a full step ago), issue data[t+2]
        if (smine && t + 1 < Lmax)
            ((short*)dbuf[1 - p])[se] = f2bf(vstage);
        float vnew = 0.f;
        if (smine && t + 2 < Lmax)
            vnew = data[((size_t)(t+2) * BB + 2*g) * DD + se];

        // ---- recurrent matmul: hi in C-rows 0..1, lo in 2..3, zero C-init
        f32x4 racc[2] = {{0.f,0.f,0.f,0.f},{0.f,0.f,0.f,0.f}};
        __builtin_amdgcn_s_setprio(1);
        #pragma unroll
        for (int half = 0; half < 2; ++half) {      // k-frags 0-3, 4-7
            if (acth) {
                #pragma unroll
                for (int i = 0; i < 4; ++i)
                    frag[i] = *(const bf16x8*)
                        &hbuf[p][(half*4 + i)*4 + quad][col][0];
            }
            #pragma unroll
            for (int i = 0; i < 4; ++i)
                #pragma unroll
                for (int s = 0; s < 2; ++s)
                    racc[s] = __builtin_amdgcn_mfma_f32_16x16x32_bf16(
                        frag[i], whh[s][half*4 + i], racc[s], 0, 0, 0);
        }

        // ---- x-projection: data[t] @ ih_w^T (bias folded below) ----
        if (actd) {
            #pragma unroll
            for (int i = 0; i < 4; ++i)
                frag[i] = *(const bf16x8*)&dbuf[p][col][i*32 + quad*8];
        }
        f32x4 xacc = {0.f, 0.f, 0.f, 0.f};
        #pragma unroll
        for (int i = 0; i < 4; ++i)
            xacc = __builtin_amdgcn_mfma_f32_16x16x32_bf16(
                frag[i], wih[i], xacc, 0, 0, 0);
        __builtin_amdgcn_s_setprio(0);

        // ---- combine hi+lo rows in-lane, spread rows over lanes 0..31 ----
        // C/D layout: col=lane&15, row=quad*4+reg; rows 0..3 all in quad 0.
        const float a0 = racc[0][0] + racc[0][2];
        const float a1 = racc[0][1] + racc[0][3];
        const float h0 = racc[1][0] + racc[1][2];
        const float h1 = racc[1][1] + racc[1][3];
        const float x0 = xacc[0];
        const float x1 = xacc[1];
        // quad1 lanes fetch row-1 values from their quad0 partner (lane^16)
        const float a1s = swz16(a1);
        const float h1s = swz16(h1);
        const float x1s = swz16(x1);
        const float a  = (rq ? a1s : a0) + bA;
        const float hv = (rq ? h1s : h0) + bH;
        const float xs = (rq ? x1s : x0) + bX;

        // ---- epilogue (one pass, lanes 0..31 meaningful) ----
        const float e   = __builtin_amdgcn_exp2f(a * -1.4426950408889634f);
        const float inv = 1.0f + e;                    // exactly 1/alpha
        const float al  = __builtin_amdgcn_rcpf(inv);  // alpha
        const float c1  = al + xs - inv;               // while pp in flight
        const float pp  = __builtin_amdgcn_exp2f(al * hv);
        const float u   = __builtin_fmaf(pp, inv, c1); // (pp-1)*inv+al+xs
        const float t2  = __builtin_amdgcn_exp2f(u * 2.8853900817779268f);
        const float th  = 1.0f - 2.0f * __builtin_amdgcn_rcpf(1.0f + t2);
        const float v   = (t < Lr) ? th : nhv;
        nhv = v;

        // ---- pack hi/lo (RNE, bit-identical to f2bf) and store h ----
        unsigned pk, pk2;
        asm("v_cvt_pk_bf16_f32 %0, %1, %1" : "=v"(pk)  : "v"(v));
        const float bhi = __uint_as_float(pk << 16);
        asm("v_cvt_pk_bf16_f32 %0, %1, %1" : "=v"(pk2) : "v"(v - bhi));
        if (quad < 2) {
            const int c = 16*w + col;           // h element index 0..255
            hbuf[1 - p][c >> 3][rq    ][c & 7] = (short)pk;
            hbuf[1 - p][c >> 3][2 + rq][c & 7] = (short)pk2;
        }

        vstage = vnew;
        // ---- barrier: LDS-visibility only; vmcnt (prefetch) stays live ----
        asm volatile("s_waitcnt lgkmcnt(0)" ::: "memory");
        __builtin_amdgcn_s_barrier();
    }

    // ---- final hidden state -> out [1, B, H] fp32 ----
    if (quad < 2)
        out[(size_t)(2*g + rq) * HH + 16*w + col] = nhv;
}

extern "C" void kernel_launch(void* const* d_in, const int* in_sizes, int n_in,
                              void* d_out, int out_size, void* d_ws, size_t ws_size,
                              hipStream_t stream) {
    const float* data    = (const float*)d_in[0];
    const float* ih_w    = (const float*)d_in[1];
    const float* ih_b    = (const float*)d_in[2];
    const float* hh_w    = (const float*)d_in[3];
    const float* hh_b    = (const float*)d_in[4];
    const int*   lengths = (const int*)d_in[5];
    float* out = (float*)d_out;

    (void)in_sizes; (void)n_in; (void)out_size; (void)d_ws; (void)ws_size;

    rnn_fused<<<dim3(BB / 2), dim3(1024), 0, stream>>>(
        data, ih_w, ih_b, hh_w, hh_b, lengths, out);
}

// Round 6
// 1215.458 us; speedup vs baseline: 4.5389x; 1.0478x over previous
//
#include <hip/hip_runtime.h>

// LinearRNNwithSoftExp on MI355X (gfx950)  T=1024, B=512, D=128, H=256.
// Round 8: remove the 3 ds_swizzles from the per-step critical path by
// DUPLICATING the A-rows: rows 4..7 mirror rows 0..3 (h0hi,h1hi,h0lo,h1lo),
// x-proj rows 4..5 mirror 0..1 (d0,d1). C/D layout (row = quad*4+reg) then
// gives quad1 an exact register copy of quad0's row sums, so each quad
// combines hi+lo locally and selects its row by rq with one cndmask —
// no cross-lane move. Bit-identical numerics; LDS loads are broadcast
// duplicates (<=2-way, free); MFMA count unchanged.
// Kept from round 7: 16 waves, wave owns 16 cols; hi/lo bf16 h fold;
// 32-lane epilogue (row = quad&1); v_cvt_pk_bf16_f32 packing; raw s_barrier
// + lgkmcnt(0) (vmcnt prefetch stays live); s_setprio around MFMA cluster;
// 2-step-ahead data prefetch; 1 barrier/step. Register-neutral (at the 128
// VGPR+AGPR cap; round 5 proved +32 = spill catastrophe).

#define BB 512
#define DD 128
#define HH 256

typedef __attribute__((ext_vector_type(8))) short bf16x8;
typedef __attribute__((ext_vector_type(4))) float f32x4;

static __device__ __forceinline__ short f2bf(float f) {
    unsigned u = __float_as_uint(f);
    u += 0x7FFFu + ((u >> 16) & 1u);   // round-to-nearest-even
    return (short)(u >> 16);
}
static __device__ __forceinline__ bf16x8 pack8(const float4 a, const float4 b) {
    bf16x8 v;
    v[0] = f2bf(a.x); v[1] = f2bf(a.y); v[2] = f2bf(a.z); v[3] = f2bf(a.w);
    v[4] = f2bf(b.x); v[5] = f2bf(b.y); v[6] = f2bf(b.z); v[7] = f2bf(b.w);
    return v;
}

__global__ __launch_bounds__(1024, 4)
void rnn_fused(const float* __restrict__ data, const float* __restrict__ ih_w,
               const float* __restrict__ ih_b, const float* __restrict__ hh_w,
               const float* __restrict__ hh_b, const int* __restrict__ lengths,
               float* __restrict__ out)
{
    const int g    = blockIdx.x;
    const int tid  = threadIdx.x;
    const int w    = tid >> 6;     // wave 0..15
    const int lane = tid & 63;
    const int col  = lane & 15;    // MFMA n-col / A-row index
    const int quad = lane >> 4;    // k-quad

    // h state, bf16 hi+lo folded into A-rows:
    // [ping][kf = k/8][row: 0=h0hi 1=h1hi 2=h0lo 3=h1lo][slot = k%8]
    __shared__ short hbuf[2][32][4][8];
    // data staging, bf16: [ping][row(2)][k(128)]
    __shared__ short dbuf[2][2][DD];

    // ---- persistent weight fragments in registers ----
    // whh[s][i]: s=0 alpha row 16w+col, s=1 hbar row 256+16w+col
    bf16x8 whh[2][8];
    #pragma unroll
    for (int s = 0; s < 2; ++s) {
        const int wrow = s*HH + 16*w + col;
        const float* src = hh_w + wrow * HH;
        #pragma unroll
        for (int i = 0; i < 8; ++i) {
            const float4 a = *(const float4*)(src + i*32 + quad*8);
            const float4 b = *(const float4*)(src + i*32 + quad*8 + 4);
            whh[s][i] = pack8(a, b);
        }
    }
    bf16x8 wih[4];
    {
        const int wrow = 16*w + col;
        const float* src = ih_w + wrow * DD;
        #pragma unroll
        for (int i = 0; i < 4; ++i) {
            const float4 a = *(const float4*)(src + i*32 + quad*8);
            const float4 b = *(const float4*)(src + i*32 + quad*8 + 4);
            wih[i] = pack8(a, b);
        }
    }

    const float bA = hh_b[      16*w + col];
    const float bH = hh_b[HH  + 16*w + col];
    const float bX = ih_b[      16*w + col];

    const int L0 = lengths[2*g];
    const int L1 = lengths[2*g + 1];
    const int Lmax = (L0 > L1) ? L0 : L1;

    // staging: lane<16 (quad==0) of wave w owns data element w*16+col
    const bool smine = (quad == 0);
    const int  se    = (w << 4) | col;

    // ---- prologue: zero h ping 0, stage data[0], prefetch data[1] ----
    for (int idx = tid; idx < 32*4*8; idx += 1024)
        ((short*)hbuf[0])[idx] = 0;
    if (smine)
        ((short*)dbuf[0])[se] = f2bf(data[(size_t)(2*g) * DD + se]);
    float vstage = 0.f;
    if (smine && 1 < Lmax)
        vstage = data[((size_t)1 * BB + 2*g) * DD + se];
    __syncthreads();

    float  nhv = 0.f;      // lanes<32: h[row=quad][16w+col]
    bf16x8 frag[4] = {};   // shared A-frags: h (col<8) then data

    // A-rows 0..3 real, rows 4..7 DUPLICATE rows 0..3 (quad1 gets a copy of
    // quad0's C rows in its own registers -> no cross-lane move needed)
    const bool acth = (col < 8);               // h rows: hbuf row = col&3
    const bool actd = (col < 8) && ((col & 3) < 2);  // d rows 0,1,4,5
    const int  rq   = quad & 1;    // row owned by this lane
    const int  Lr   = rq ? L1 : L0;

    for (int t = 0; t < Lmax; ++t) {
        const int p = t & 1;

        // ---- publish data[t+1] (loaded a full step ago), issue data[t+2]
        if (smine && t + 1 < Lmax)
            ((short*)dbuf[1 - p])[se] = f2bf(vstage);
        float vnew = 0.f;
        if (smine && t + 2 < Lmax)
            vnew = data[((size_t)(t+2) * BB + 2*g) * DD + se];

        // ---- recurrent matmul: hi in C-regs 0..1, lo in 2..3 (both quads)
        f32x4 racc[2] = {{0.f,0.f,0.f,0.f},{0.f,0.f,0.f,0.f}};
        __builtin_amdgcn_s_setprio(1);
        #pragma unroll
        for (int half = 0; half < 2; ++half) {      // k-frags 0-3, 4-7
            if (acth) {
                #pragma unroll
                for (int i = 0; i < 4; ++i)
                    frag[i] = *(const bf16x8*)
                        &hbuf[p][(half*4 + i)*4 + quad][col & 3][0];
            }
            #pragma unroll
            for (int i = 0; i < 4; ++i)
                #pragma unroll
                for (int s = 0; s < 2; ++s)
                    racc[s] = __builtin_amdgcn_mfma_f32_16x16x32_bf16(
                        frag[i], whh[s][half*4 + i], racc[s], 0, 0, 0);
        }

        // ---- x-projection: data[t] @ ih_w^T (bias folded below) ----
        if (actd) {
            #pragma unroll
            for (int i = 0; i < 4; ++i)
                frag[i] = *(const bf16x8*)&dbuf[p][col & 1][i*32 + quad*8];
        }
        f32x4 xacc = {0.f, 0.f, 0.f, 0.f};
        #pragma unroll
        for (int i = 0; i < 4; ++i)
            xacc = __builtin_amdgcn_mfma_f32_16x16x32_bf16(
                frag[i], wih[i], xacc, 0, 0, 0);
        __builtin_amdgcn_s_setprio(0);

        // ---- combine hi+lo in-lane; each quad holds BOTH row sums ----
        // C/D: row = quad*4 + reg. Rows 4..7 duplicate 0..3, so quad1's
        // regs 0..3 mirror quad0's. Select own row by rq (1 cndmask each).
        const float a_s0 = racc[0][0] + racc[0][2];
        const float a_s1 = racc[0][1] + racc[0][3];
        const float h_s0 = racc[1][0] + racc[1][2];
        const float h_s1 = racc[1][1] + racc[1][3];
        const float a  = (rq ? a_s1 : a_s0) + bA;
        const float hv = (rq ? h_s1 : h_s0) + bH;
        const float xs = (rq ? xacc[1] : xacc[0]) + bX;

        // ---- epilogue (one pass, lanes 0..31 meaningful) ----
        const float e   = __builtin_amdgcn_exp2f(a * -1.4426950408889634f);
        const float inv = 1.0f + e;                    // exactly 1/alpha
        const float al  = __builtin_amdgcn_rcpf(inv);  // alpha
        const float c1  = al + xs - inv;               // while pp in flight
        const float pp  = __builtin_amdgcn_exp2f(al * hv);
        const float u   = __builtin_fmaf(pp, inv, c1); // (pp-1)*inv+al+xs
        const float t2  = __builtin_amdgcn_exp2f(u * 2.8853900817779268f);
        const float th  = 1.0f - 2.0f * __builtin_amdgcn_rcpf(1.0f + t2);
        const float v   = (t < Lr) ? th : nhv;
        nhv = v;

        // ---- pack hi/lo (RNE, bit-identical to f2bf) and store h ----
        unsigned pk, pk2;
        asm("v_cvt_pk_bf16_f32 %0, %1, %1" : "=v"(pk)  : "v"(v));
        const float bhi = __uint_as_float(pk << 16);
        asm("v_cvt_pk_bf16_f32 %0, %1, %1" : "=v"(pk2) : "v"(v - bhi));
        if (quad < 2) {
            const int c = 16*w + col;           // h element index 0..255
            hbuf[1 - p][c >> 3][rq    ][c & 7] = (short)pk;
            hbuf[1 - p][c >> 3][2 + rq][c & 7] = (short)pk2;
        }

        vstage = vnew;
        // ---- barrier: LDS-visibility only; vmcnt (prefetch) stays live ----
        asm volatile("s_waitcnt lgkmcnt(0)" ::: "memory");
        __builtin_amdgcn_s_barrier();
    }

    // ---- final hidden state -> out [1, B, H] fp32 ----
    if (quad < 2)
        out[(size_t)(2*g + rq) * HH + 16*w + col] = nhv;
}

extern "C" void kernel_launch(void* const* d_in, const int* in_sizes, int n_in,
                              void* d_out, int out_size, void* d_ws, size_t ws_size,
                              hipStream_t stream) {
    const float* data    = (const float*)d_in[0];
    const float* ih_w    = (const float*)d_in[1];
    const float* ih_b    = (const float*)d_in[2];
    const float* hh_w    = (const float*)d_in[3];
    const float* hh_b    = (const float*)d_in[4];
    const int*   lengths = (const int*)d_in[5];
    float* out = (float*)d_out;

    (void)in_sizes; (void)n_in; (void)out_size; (void)d_ws; (void)ws_size;

    rnn_fused<<<dim3(BB / 2), dim3(1024), 0, stream>>>(
        data, ih_w, ih_b, hh_w, hh_b, lengths, out);
}